// Round 1
// baseline (545.614 us; speedup 1.0000x reference)
//
#include <hip/hip_runtime.h>
#include <math.h>

// ============================================================================
// EnhancedGrayscaleCombinedLoss: 0.3 * L2 + 0.7 * (1 - MS-SSIM(3 scales))
// Shapes: B=64, C=1, H=176, W=1008 (fp32). Output: [total, l2, ssim_loss].
//
// MS-SSIM windows (asym): scale0 11x15 pad(5,7), scale1 9x12 pad(4,6),
// scale2 7x10 pad(3,5). Even widths -> conv out width W+1 at scales 1,2.
// Separable window = outer(gauss_h, gauss_w).
// ============================================================================

static __device__ __forceinline__ double wave_reduce_d(double v) {
#pragma unroll
    for (int off = 32; off > 0; off >>= 1)
        v += __shfl_down(v, off, 64);
    return v;
}

// ---------------- pool 2x2 (+ fused L2 reduction over ORIGINAL pixels) ------

__global__ __launch_bounds__(256)
void pool_l2_kernel(const float* __restrict__ X, const float* __restrict__ Y,
                    float* __restrict__ Xp, float* __restrict__ Yp,
                    int B, int H, int W, double* __restrict__ accL2)
{
    const int H2 = H >> 1, W2 = W >> 1;
    const int total = B * H2 * W2;
    double l2 = 0.0;
    for (int e = blockIdx.x * 256 + threadIdx.x; e < total; e += gridDim.x * 256) {
        const int w2 = e % W2;
        const int t  = e / W2;
        const int h2 = t % H2;
        const int b  = t / H2;
        const size_t base = ((size_t)(b * H + 2 * h2)) * W + 2 * w2;
        const float2 x0 = *(const float2*)(X + base);
        const float2 x1 = *(const float2*)(X + base + W);
        const float2 y0 = *(const float2*)(Y + base);
        const float2 y1 = *(const float2*)(Y + base + W);
        Xp[e] = 0.25f * ((x0.x + x0.y) + (x1.x + x1.y));
        Yp[e] = 0.25f * ((y0.x + y0.y) + (y1.x + y1.y));
        const float d0 = x0.x - y0.x, d1 = x0.y - y0.y;
        const float d2 = x1.x - y1.x, d3 = x1.y - y1.y;
        l2 += (double)(d0 * d0) + (double)(d1 * d1) +
              (double)(d2 * d2) + (double)(d3 * d3);
    }
    __shared__ double red[4];
    const int lane = threadIdx.x & 63, wv = threadIdx.x >> 6;
    l2 = wave_reduce_d(l2);
    if (lane == 0) red[wv] = l2;
    __syncthreads();
    if (threadIdx.x == 0) atomicAdd(accL2, red[0] + red[1] + red[2] + red[3]);
}

__global__ __launch_bounds__(256)
void pool_kernel(const float* __restrict__ X, const float* __restrict__ Y,
                 float* __restrict__ Xp, float* __restrict__ Yp,
                 int B, int H, int W)
{
    const int H2 = H >> 1, W2 = W >> 1;
    const int total = B * H2 * W2;
    for (int e = blockIdx.x * 256 + threadIdx.x; e < total; e += gridDim.x * 256) {
        const int w2 = e % W2;
        const int t  = e / W2;
        const int h2 = t % H2;
        const int b  = t / H2;
        const size_t base = ((size_t)(b * H + 2 * h2)) * W + 2 * w2;
        const float2 x0 = *(const float2*)(X + base);
        const float2 x1 = *(const float2*)(X + base + W);
        const float2 y0 = *(const float2*)(Y + base);
        const float2 y1 = *(const float2*)(Y + base + W);
        Xp[e] = 0.25f * ((x0.x + x0.y) + (x1.x + x1.y));
        Yp[e] = 0.25f * ((y0.x + y0.y) + (y1.x + y1.y));
    }
}

// ---------------- fused separable-conv SSIM (one scale per launch) ----------
// Block computes a TH x TW output tile. acc[0]+=sum(l*cs), acc[1]+=sum(cs).

template <int KH, int KW, int TH, int TW>
__global__ __launch_bounds__(256)
void ssim_kernel(const float* __restrict__ X, const float* __restrict__ Y,
                 int H, int W, int Wout, double* __restrict__ acc)
{
    constexpr int PADH = KH / 2, PADW = KW / 2;
    constexpr int RH = TH + KH - 1;   // halo rows
    constexpr int RW = TW + KW - 1;   // halo cols

    __shared__ float xs[RH][RW];
    __shared__ float ys[RH][RW];
    __shared__ float hx [RH][TW];
    __shared__ float hy [RH][TW];
    __shared__ float hxx[RH][TW];
    __shared__ float hyy[RH][TW];
    __shared__ float hxy[RH][TW];
    __shared__ float gh_s[KH];
    __shared__ float gw_s[KW];
    __shared__ double red[2][4];

    const int b   = blockIdx.z;
    const int i0  = blockIdx.y * TH;
    const int j0  = blockIdx.x * TW;
    const int tid = threadIdx.x;

    if (tid == 0) {
        // gauss_1d(KH, 1.5) and gauss_1d(KW, 1.5*KW/KH), centered at K/2
        const double sh = 1.5;
        const double sw = 1.5 * (double)KW / (double)KH;
        double s = 0.0;
#pragma unroll
        for (int i = 0; i < KH; ++i) {
            const double g = exp(-(double)((i - KH / 2) * (i - KH / 2)) / (2.0 * sh * sh));
            gh_s[i] = (float)g; s += g;
        }
#pragma unroll
        for (int i = 0; i < KH; ++i) gh_s[i] = (float)((double)gh_s[i] / s);
        s = 0.0;
#pragma unroll
        for (int i = 0; i < KW; ++i) {
            const double g = exp(-(double)((i - KW / 2) * (i - KW / 2)) / (2.0 * sw * sw));
            gw_s[i] = (float)g; s += g;
        }
#pragma unroll
        for (int i = 0; i < KW; ++i) gw_s[i] = (float)((double)gw_s[i] / s);
    }

    // ---- load halo tile (zero-padded) ----
    const float* Xb = X + (size_t)b * H * W;
    const float* Yb = Y + (size_t)b * H * W;
    for (int idx = tid; idx < RH * RW; idx += 256) {
        const int r  = idx / RW, c = idx % RW;
        const int gi = i0 - PADH + r;
        const int gj = j0 - PADW + c;
        float xv = 0.f, yv = 0.f;
        if (gi >= 0 && gi < H && gj >= 0 && gj < W) {
            xv = Xb[(size_t)gi * W + gj];
            yv = Yb[(size_t)gi * W + gj];
        }
        xs[r][c] = xv;
        ys[r][c] = yv;
    }
    __syncthreads();

    // ---- horizontal gaussian pass: 5 maps ----
    for (int idx = tid; idx < RH * TW; idx += 256) {
        const int r = idx / TW, c = idx % TW;
        float sx = 0.f, sy = 0.f, sxx = 0.f, syy = 0.f, sxy = 0.f;
#pragma unroll
        for (int k = 0; k < KW; ++k) {
            const float g  = gw_s[k];
            const float xv = xs[r][c + k];
            const float yv = ys[r][c + k];
            sx  += g * xv;
            sy  += g * yv;
            sxx += g * xv * xv;
            syy += g * yv * yv;
            sxy += g * xv * yv;
        }
        hx [r][c] = sx;  hy [r][c] = sy;
        hxx[r][c] = sxx; hyy[r][c] = syy; hxy[r][c] = sxy;
    }
    __syncthreads();

    // ---- vertical gaussian pass + SSIM + local accumulate ----
    double lcs_sum = 0.0, cs_sum = 0.0;
    for (int idx = tid; idx < TH * TW; idx += 256) {
        const int ti = idx / TW, tj = idx % TW;
        const int gi = i0 + ti, gj = j0 + tj;
        if (gi < H && gj < Wout) {
            float mx = 0.f, my = 0.f, mxx = 0.f, myy = 0.f, mxy = 0.f;
#pragma unroll
            for (int k = 0; k < KH; ++k) {
                const float g = gh_s[k];
                mx  += g * hx [ti + k][tj];
                my  += g * hy [ti + k][tj];
                mxx += g * hxx[ti + k][tj];
                myy += g * hyy[ti + k][tj];
                mxy += g * hxy[ti + k][tj];
            }
            const float mx2 = mx * mx, my2 = my * my, mxmy = mx * my;
            const float vx = mxx - mx2, vy = myy - my2, vxy = mxy - mxmy;
            const float l  = (2.f * mxmy + 1e-4f) / (mx2 + my2 + 1e-4f);
            const float cs = (2.f * vxy + 9e-4f) / (vx + vy + 9e-4f);
            lcs_sum += (double)(l * cs);
            cs_sum  += (double)cs;
        }
    }

    lcs_sum = wave_reduce_d(lcs_sum);
    cs_sum  = wave_reduce_d(cs_sum);
    const int lane = tid & 63, wv = tid >> 6;
    if (lane == 0) { red[0][wv] = lcs_sum; red[1][wv] = cs_sum; }
    __syncthreads();
    if (tid == 0) {
        atomicAdd(&acc[0], red[0][0] + red[0][1] + red[0][2] + red[0][3]);
        atomicAdd(&acc[1], red[1][0] + red[1][1] + red[1][2] + red[1][3]);
    }
}

// ---------------- finalize ----------------

__global__ void final_kernel(const double* __restrict__ acc, float* __restrict__ out)
{
    // acc: [0]=l2_sum, [1,2]=s0 (lcs,cs), [3,4]=s1, [5,6]=s2
    const double N0 = 64.0 * 176.0 * 1008.0;  // also the L2 element count
    const double N1 = 64.0 * 88.0  * 505.0;
    const double N2 = 64.0 * 44.0  * 253.0;
    const double l2  = acc[0] / N0;
    const double cs0 = acc[2] / N0;
    const double cs1 = acc[4] / N1;
    const double s2  = acc[5] / N2;
    const double wsum = 0.0448 + 0.2856 + 0.3001;
    const double w0 = 0.0448 / wsum, w1 = 0.2856 / wsum, w2 = 0.3001 / wsum;
    const double ms = pow(cs0, w0) * pow(cs1, w1) * pow(s2, w2);
    const double ssim_loss = 1.0 - ms;
    const double total = 0.3 * l2 + 0.7 * ssim_loss;
    out[0] = (float)total;
    out[1] = (float)l2;
    out[2] = (float)ssim_loss;
}

// ---------------- launch ----------------

extern "C" void kernel_launch(void* const* d_in, const int* in_sizes, int n_in,
                              void* d_out, int out_size, void* d_ws, size_t ws_size,
                              hipStream_t stream)
{
    (void)in_sizes; (void)n_in; (void)out_size; (void)ws_size;

    const float* X = (const float*)d_in[0];
    const float* Y = (const float*)d_in[1];
    float* out = (float*)d_out;

    constexpr int B = 64, H = 176, W = 1008;
    constexpr int H1 = H / 2, W1 = W / 2;   // 88, 504
    constexpr int H2 = H / 4, W2 = W / 4;   // 44, 252
    constexpr int n1 = B * H1 * W1;         // 2,838,528
    constexpr int n2 = B * H2 * W2;         //   709,632

    // workspace layout: 7 doubles (accumulators), then pooled images
    double* acc = (double*)d_ws;
    float* x1 = (float*)((char*)d_ws + 256);
    float* y1 = x1 + n1;
    float* x2 = y1 + n1;
    float* y2 = x2 + n2;

    hipMemsetAsync(acc, 0, 7 * sizeof(double), stream);

    {
        int blocks = (n1 + 255) / 256; if (blocks > 2048) blocks = 2048;
        pool_l2_kernel<<<blocks, 256, 0, stream>>>(X, Y, x1, y1, B, H, W, &acc[0]);
    }
    {
        int blocks = (n2 + 255) / 256; if (blocks > 2048) blocks = 2048;
        pool_kernel<<<blocks, 256, 0, stream>>>(x1, y1, x2, y2, B, H1, W1);
    }

    // scale 0: 176x1008, win 11x15, out 176x1008
    ssim_kernel<11, 15, 16, 64>
        <<<dim3((1008 + 63) / 64, (176 + 15) / 16, B), 256, 0, stream>>>(
            X, Y, H, W, 1008, &acc[1]);
    // scale 1: 88x504, win 9x12, out 88x505 (even kw -> W+1)
    ssim_kernel<9, 12, 16, 64>
        <<<dim3((505 + 63) / 64, (88 + 15) / 16, B), 256, 0, stream>>>(
            x1, y1, H1, W1, 505, &acc[3]);
    // scale 2: 44x252, win 7x10, out 44x253
    ssim_kernel<7, 10, 16, 64>
        <<<dim3((253 + 63) / 64, (44 + 15) / 16, B), 256, 0, stream>>>(
            x2, y2, H2, W2, 253, &acc[5]);

    final_kernel<<<1, 1, 0, stream>>>(acc, out);
}

// Round 2
// 282.626 us; speedup vs baseline: 1.9305x; 1.9305x over previous
//
#include <hip/hip_runtime.h>
#include <math.h>

// ============================================================================
// EnhancedGrayscaleCombinedLoss: 0.3 * L2 + 0.7 * (1 - MS-SSIM(3 scales))
// B=64, C=1, H=176, W=1008 fp32. Out: [total, l2, ssim_loss].
// Scale0: win 11x15 pad(5,7) out 176x1008; scale1: 9x12 pad(4,6) out 88x505;
// scale2: 7x10 pad(3,5) out 44x253. Separable window (outer product).
//
// R1 design: fused separable SSIM, NO input LDS staging (global L1 reads),
// SoA h-map planes in LDS (33 KB -> 4 blocks/CU), register-blocked v-pass
// (4 rows/thread), device-precomputed windows, per-block partials (no
// atomic contention), single final reduce+formula kernel.
// ============================================================================

#define C1F 1e-4f
#define C2F 9e-4f

static __device__ __forceinline__ double wave_reduce_d(double v) {
#pragma unroll
    for (int off = 32; off > 0; off >>= 1)
        v += __shfl_down(v, off, 64);
    return v;
}

// ---------------- window generation (device, one thread, once) --------------

static __device__ void gen_gauss(float* dst, int K, double sigma) {
    double g[16];
    double s = 0.0;
    for (int i = 0; i < K; ++i) {
        const int d = i - K / 2;
        g[i] = exp(-(double)(d * d) / (2.0 * sigma * sigma));
        s += g[i];
    }
    for (int i = 0; i < K; ++i) dst[i] = (float)(g[i] / s);
}

// ---------------- pool 2x2 + fused L2 + window init -------------------------

template <int B, int H, int W>
__global__ __launch_bounds__(256)
void pool_l2_kernel(const float* __restrict__ X, const float* __restrict__ Y,
                    float* __restrict__ Xp, float* __restrict__ Yp,
                    double* __restrict__ part, float* __restrict__ win)
{
    constexpr int H2 = H / 2, W2 = W / 2, NP = W2 / 2;  // NP float4-pairs/row
    constexpr int total = B * H2 * NP;
    const int tid = threadIdx.x;
    double l2 = 0.0;
    for (int e = blockIdx.x * 256 + tid; e < total; e += gridDim.x * 256) {
        const int p  = e % NP;
        const int t  = e / NP;
        const int h2 = t % H2;
        const int b  = t / H2;
        const size_t base = ((size_t)(b * H + 2 * h2)) * W + 4 * p;
        const float4 x0 = *(const float4*)(X + base);
        const float4 x1 = *(const float4*)(X + base + W);
        const float4 y0 = *(const float4*)(Y + base);
        const float4 y1 = *(const float4*)(Y + base + W);
        const size_t ob = ((size_t)(b * H2 + h2)) * W2 + 2 * p;
        *(float2*)(Xp + ob) = make_float2(0.25f * ((x0.x + x0.y) + (x1.x + x1.y)),
                                          0.25f * ((x0.z + x0.w) + (x1.z + x1.w)));
        *(float2*)(Yp + ob) = make_float2(0.25f * ((y0.x + y0.y) + (y1.x + y1.y)),
                                          0.25f * ((y0.z + y0.w) + (y1.z + y1.w)));
        float s = 0.f, d;
        d = x0.x - y0.x; s += d * d;
        d = x0.y - y0.y; s += d * d;
        d = x0.z - y0.z; s += d * d;
        d = x0.w - y0.w; s += d * d;
        d = x1.x - y1.x; s += d * d;
        d = x1.y - y1.y; s += d * d;
        d = x1.z - y1.z; s += d * d;
        d = x1.w - y1.w; s += d * d;
        l2 += (double)s;
    }
    __shared__ double red[4];
    l2 = wave_reduce_d(l2);
    if ((tid & 63) == 0) red[tid >> 6] = l2;
    __syncthreads();
    if (tid == 0) part[blockIdx.x] = red[0] + red[1] + red[2] + red[3];

    if (blockIdx.x == 0 && tid == 0) {
        // gh at +0/+32/+64, gw at +16/+48/+80 (float offsets)
        gen_gauss(win + 0,  11, 1.5);
        gen_gauss(win + 16, 15, 1.5 * 15.0 / 11.0);
        gen_gauss(win + 32, 9,  1.5);
        gen_gauss(win + 48, 12, 1.5 * 12.0 / 9.0);
        gen_gauss(win + 64, 7,  1.5);
        gen_gauss(win + 80, 10, 1.5 * 10.0 / 7.0);
    }
}

// ---------------- pool 2x2 (no reduction) -----------------------------------

template <int B, int H, int W>
__global__ __launch_bounds__(256)
void pool_kernel(const float* __restrict__ Xi, const float* __restrict__ Yi,
                 float* __restrict__ Xp, float* __restrict__ Yp)
{
    constexpr int H2 = H / 2, W2 = W / 2, NP = W2 / 2;
    constexpr int total = B * H2 * NP;
    for (int e = blockIdx.x * 256 + threadIdx.x; e < total; e += gridDim.x * 256) {
        const int p  = e % NP;
        const int t  = e / NP;
        const int h2 = t % H2;
        const int b  = t / H2;
        const size_t base = ((size_t)(b * H + 2 * h2)) * W + 4 * p;
        const float4 x0 = *(const float4*)(Xi + base);
        const float4 x1 = *(const float4*)(Xi + base + W);
        const float4 y0 = *(const float4*)(Yi + base);
        const float4 y1 = *(const float4*)(Yi + base + W);
        const size_t ob = ((size_t)(b * H2 + h2)) * W2 + 2 * p;
        *(float2*)(Xp + ob) = make_float2(0.25f * ((x0.x + x0.y) + (x1.x + x1.y)),
                                          0.25f * ((x0.z + x0.w) + (x1.z + x1.w)));
        *(float2*)(Yp + ob) = make_float2(0.25f * ((y0.x + y0.y) + (y1.x + y1.y)),
                                          0.25f * ((y0.z + y0.w) + (y1.z + y1.w)));
    }
}

// ---------------- fused separable SSIM (one scale per launch) ---------------
// Tile 16x64 outputs, 256 threads. h-pass: direct global reads (L1-hot,
// per-tap coalesced), writes 5 SoA planes to LDS. v-pass: 4 rows/thread
// register-blocked sliding accumulation. Per-block partials [lcs, cs].

template <int KH, int KW>
__global__ __launch_bounds__(256)
void ssim_kernel(const float* __restrict__ X, const float* __restrict__ Y,
                 const float* __restrict__ ghp, const float* __restrict__ gwp,
                 int H, int W, int Wout, double* __restrict__ part)
{
    constexpr int TH = 16, TW = 64;
    constexpr int PADH = KH / 2, PADW = KW / 2;
    constexpr int RH = TH + KH - 1;

    __shared__ float hm[5][RH][TW];
    __shared__ double red[2][4];

    const int tid = threadIdx.x;
    const int c   = tid & 63;
    const int rg  = tid >> 6;
    const int b   = blockIdx.z;
    const int i0  = blockIdx.y * TH;
    const int j0  = blockIdx.x * TW;

    float gw[KW];
#pragma unroll
    for (int k = 0; k < KW; ++k) gw[k] = gwp[k];

    const float* Xb = X + (size_t)b * H * W;
    const float* Yb = Y + (size_t)b * H * W;
    const bool colsafe = (j0 >= PADW) && (j0 + TW - 1 + (KW - 1 - PADW) < W);
    const int gj0 = j0 - PADW + c;   // global col of window tap 0 for this col

    // ---- horizontal pass: 5 maps into LDS SoA planes ----
    for (int r = rg; r < RH; r += 4) {
        const int gi = i0 - PADH + r;
        float sx = 0.f, sy = 0.f, sxx = 0.f, syy = 0.f, sxy = 0.f;
        if (gi >= 0 && gi < H) {
            const float* xrow = Xb + (size_t)gi * W + gj0;
            const float* yrow = Yb + (size_t)gi * W + gj0;
            if (colsafe) {
#pragma unroll
                for (int k = 0; k < KW; ++k) {
                    const float xv = xrow[k], yv = yrow[k];
                    const float gx = gw[k] * xv, gy = gw[k] * yv;
                    sx += gx; sy += gy;
                    sxx = fmaf(gx, xv, sxx);
                    syy = fmaf(gy, yv, syy);
                    sxy = fmaf(gx, yv, sxy);
                }
            } else {
#pragma unroll
                for (int k = 0; k < KW; ++k) {
                    float xv = 0.f, yv = 0.f;
                    if ((unsigned)(gj0 + k) < (unsigned)W) { xv = xrow[k]; yv = yrow[k]; }
                    const float gx = gw[k] * xv, gy = gw[k] * yv;
                    sx += gx; sy += gy;
                    sxx = fmaf(gx, xv, sxx);
                    syy = fmaf(gy, yv, syy);
                    sxy = fmaf(gy, xv, sxy);
                }
            }
        }
        hm[0][r][c] = sx;  hm[1][r][c] = sy;
        hm[2][r][c] = sxx; hm[3][r][c] = syy; hm[4][r][c] = sxy;
    }
    __syncthreads();

    // ---- vertical pass: 4 outputs per thread (rows 4*rg .. 4*rg+3) ----
    float gh[KH];
#pragma unroll
    for (int k = 0; k < KH; ++k) gh[k] = ghp[k];

    float acc[4][5];
#pragma unroll
    for (int r = 0; r < 4; ++r)
#pragma unroll
        for (int m = 0; m < 5; ++m) acc[r][m] = 0.f;

#pragma unroll
    for (int j = 0; j < KH + 3; ++j) {
        float hv[5];
#pragma unroll
        for (int m = 0; m < 5; ++m) hv[m] = hm[m][4 * rg + j][c];
#pragma unroll
        for (int r = 0; r < 4; ++r) {
            const int kk = j - r;
            if (kk >= 0 && kk < KH) {
#pragma unroll
                for (int m = 0; m < 5; ++m)
                    acc[r][m] = fmaf(gh[kk], hv[m], acc[r][m]);
            }
        }
    }

    double lcs_sum = 0.0, cs_sum = 0.0;
    const int gj  = j0 + c;
    const int gi0 = i0 + 4 * rg;
#pragma unroll
    for (int r = 0; r < 4; ++r) {
        if (gi0 + r < H && gj < Wout) {
            const float mx = acc[r][0], my = acc[r][1];
            const float mxx = acc[r][2], myy = acc[r][3], mxy = acc[r][4];
            const float mx2 = mx * mx, my2 = my * my, mxmy = mx * my;
            const float vx = mxx - mx2, vy = myy - my2, vxy = mxy - mxmy;
            const float l  = __fdividef(fmaf(2.f, mxmy, C1F), (mx2 + my2) + C1F);
            const float cs = __fdividef(fmaf(2.f, vxy,  C2F), (vx + vy) + C2F);
            lcs_sum += (double)(l * cs);
            cs_sum  += (double)cs;
        }
    }

    lcs_sum = wave_reduce_d(lcs_sum);
    cs_sum  = wave_reduce_d(cs_sum);
    if ((tid & 63) == 0) { red[0][tid >> 6] = lcs_sum; red[1][tid >> 6] = cs_sum; }
    __syncthreads();
    if (tid == 0) {
        const int bid = blockIdx.x + gridDim.x * (blockIdx.y + gridDim.y * blockIdx.z);
        part[2 * bid]     = red[0][0] + red[0][1] + red[0][2] + red[0][3];
        part[2 * bid + 1] = red[1][0] + red[1][1] + red[1][2] + red[1][3];
    }
}

// ---------------- final reduce + formula ------------------------------------

__global__ __launch_bounds__(256)
void final_kernel(const double* __restrict__ part, float* __restrict__ out)
{
    constexpr int NL2 = 2048, NB0 = 11264, NB1 = 3072, NB2 = 768;
    const double* pl2 = part;
    const double* p0  = part + NL2;
    const double* p1  = p0 + 2 * NB0;
    const double* p2  = p1 + 2 * NB1;
    const int tid = threadIdx.x;

    double sl2 = 0, slcs0 = 0, scs0 = 0, slcs1 = 0, scs1 = 0, slcs2 = 0, scs2 = 0;
    for (int i = tid; i < NL2; i += 256) sl2 += pl2[i];
    for (int i = tid; i < NB0; i += 256) { slcs0 += p0[2 * i]; scs0 += p0[2 * i + 1]; }
    for (int i = tid; i < NB1; i += 256) { slcs1 += p1[2 * i]; scs1 += p1[2 * i + 1]; }
    for (int i = tid; i < NB2; i += 256) { slcs2 += p2[2 * i]; scs2 += p2[2 * i + 1]; }

    __shared__ double red[7][4];
    double v[7] = { sl2, slcs0, scs0, slcs1, scs1, slcs2, scs2 };
#pragma unroll
    for (int s = 0; s < 7; ++s) {
        const double r = wave_reduce_d(v[s]);
        if ((tid & 63) == 0) red[s][tid >> 6] = r;
    }
    __syncthreads();
    if (tid == 0) {
        double a[7];
#pragma unroll
        for (int s = 0; s < 7; ++s) a[s] = red[s][0] + red[s][1] + red[s][2] + red[s][3];
        const double NE0 = 64.0 * 176.0 * 1008.0;
        const double NE1 = 64.0 * 88.0  * 505.0;
        const double NE2 = 64.0 * 44.0  * 253.0;
        const double l2  = a[0] / NE0;
        const double cs0 = a[2] / NE0;
        const double cs1 = a[4] / NE1;
        const double s2  = a[5] / NE2;   // lcs mean of last scale
        const double wsum = 0.0448 + 0.2856 + 0.3001;
        const double w0 = 0.0448 / wsum, w1 = 0.2856 / wsum, w2 = 0.3001 / wsum;
        const double ms = pow(cs0, w0) * pow(cs1, w1) * pow(s2, w2);
        const double ssim_loss = 1.0 - ms;
        const double total = 0.3 * l2 + 0.7 * ssim_loss;
        out[0] = (float)total;
        out[1] = (float)l2;
        out[2] = (float)ssim_loss;
    }
}

// ---------------- launch ----------------------------------------------------

extern "C" void kernel_launch(void* const* d_in, const int* in_sizes, int n_in,
                              void* d_out, int out_size, void* d_ws, size_t ws_size,
                              hipStream_t stream)
{
    (void)in_sizes; (void)n_in; (void)out_size; (void)ws_size;

    const float* X = (const float*)d_in[0];
    const float* Y = (const float*)d_in[1];
    float* out = (float*)d_out;

    constexpr int B = 64, H = 176, W = 1008;
    constexpr int H1 = 88, W1 = 504;
    constexpr int H2c = 44, W2c = 252;
    constexpr int n1 = B * H1 * W1;    // 2,838,528
    constexpr int n2 = B * H2c * W2c;  //   709,632

    // workspace: [win 96 floats][pad][partials 32256 doubles][x1 y1 x2 y2]
    char* ws = (char*)d_ws;
    float*  win  = (float*)ws;
    double* part = (double*)(ws + 512);
    float* x1 = (float*)(ws + 512 + 32256 * 8);
    float* y1 = x1 + n1;
    float* x2 = y1 + n1;
    float* y2 = x2 + n2;

    double* pl2 = part;                 // 2048
    double* p0  = part + 2048;          // 2*11264
    double* p1  = p0 + 2 * 11264;       // 2*3072
    double* p2  = p1 + 2 * 3072;        // 2*768

    pool_l2_kernel<64, 176, 1008><<<2048, 256, 0, stream>>>(X, Y, x1, y1, pl2, win);
    pool_kernel<64, 88, 504><<<1386, 256, 0, stream>>>(x1, y1, x2, y2);

    ssim_kernel<11, 15><<<dim3(16, 11, 64), 256, 0, stream>>>(
        X, Y, win + 0, win + 16, H, W, 1008, p0);
    ssim_kernel<9, 12><<<dim3(8, 6, 64), 256, 0, stream>>>(
        x1, y1, win + 32, win + 48, H1, W1, 505, p1);
    ssim_kernel<7, 10><<<dim3(4, 3, 64), 256, 0, stream>>>(
        x2, y2, win + 64, win + 80, H2c, W2c, 253, p2);

    final_kernel<<<1, 256, 0, stream>>>(part, out);
}